// Round 1
// baseline (359.469 us; speedup 1.0000x reference)
//
#include <hip/hip_runtime.h>
#include <hip/hip_bf16.h>

#define BB 32
#define LL 1024
#define DD 768

typedef short bf16x8 __attribute__((ext_vector_type(8)));
typedef float f32x4 __attribute__((ext_vector_type(4)));

// ---------------------------------------------------------------------------
// Pass 1: fp32 -> bf16 convert (Q and w3*K), plus q_logit / k_logit dots.
// One wave per row (256-thr blocks = 4 rows/block); lane owns 3 float4 chunks
// at stride 64 (768 floats = 192 float4 = 64 lanes x 3). Shuffle-only reduce.
// ---------------------------------------------------------------------------
__device__ __forceinline__ unsigned short f2bf(float f) {
    // RNE f32->bf16 (inputs are finite normals; no NaN handling needed)
    unsigned u = __builtin_bit_cast(unsigned, f);
    u += 0x7fffu + ((u >> 16) & 1u);
    return (unsigned short)(u >> 16);
}

__global__ __launch_bounds__(256) void convert_kernel(
    const float* __restrict__ Q, const float* __restrict__ K,
    const float* __restrict__ w1, const float* __restrict__ w2,
    const float* __restrict__ w3,
    unsigned short* __restrict__ Qb, unsigned short* __restrict__ Kb,
    float* __restrict__ qlog, float* __restrict__ klog)
{
    const int ln  = threadIdx.x & 63;
    const int row = blockIdx.x * 4 + (threadIdx.x >> 6);
    const size_t base = (size_t)row * DD;

    float qdot = 0.f, kdot = 0.f;
    #pragma unroll
    for (int c = 0; c < 3; ++c) {
        const int idx = c * 64 + ln;  // float4 index within the row
        float4 qv  = ((const float4*)(Q + base))[idx];
        float4 kv  = ((const float4*)(K + base))[idx];
        float4 w1v = ((const float4*)w1)[idx];
        float4 w2v = ((const float4*)w2)[idx];
        float4 w3v = ((const float4*)w3)[idx];

        qdot += qv.x*w1v.x + qv.y*w1v.y + qv.z*w1v.z + qv.w*w1v.w;
        kdot += kv.x*w2v.x + kv.y*w2v.y + kv.z*w2v.z + kv.w*w2v.w;

        ushort4 pq, pk;
        pq.x = f2bf(qv.x); pq.y = f2bf(qv.y); pq.z = f2bf(qv.z); pq.w = f2bf(qv.w);
        pk.x = f2bf(kv.x * w3v.x); pk.y = f2bf(kv.y * w3v.y);
        pk.z = f2bf(kv.z * w3v.z); pk.w = f2bf(kv.w * w3v.w);
        ((ushort4*)(Qb + base))[idx] = pq;
        ((ushort4*)(Kb + base))[idx] = pk;
    }

    #pragma unroll
    for (int off = 32; off > 0; off >>= 1) {
        qdot += __shfl_down(qdot, off, 64);
        kdot += __shfl_down(kdot, off, 64);
    }
    if (ln == 0) { qlog[row] = qdot; klog[row] = kdot; }
}

// ---------------------------------------------------------------------------
// Pass 2: batched GEMM  C[b] = Qb[b] @ Kb[b]^T  (+ q_logit row + k_logit col)
// 128x128 tile, BK=32, 4 waves in 2x2, 4x4 accs of 16x16x32 bf16 MFMA.
//
// R(this): 3-deep LDS ring + COUNTED vmcnt (T3/T4). The old 2-buffer loop
// drained vmcnt to 0 at every __syncthreads (24x), exposing full load latency
// against only ~16 MFMA of cover -> MfmaUtil 20%. Now tile t+2 is issued
// while computing tile t; the end-of-tile wait is vmcnt(4): tile t+1 (issued
// one FULL tile ago) must have landed, tile t+2's 4 loads stay in flight.
// Provable stagger: buf (t+2)%3 was last read at tile t-1, whose ds_reads are
// drained (explicit lgkmcnt(0)) before the barrier that precedes this stage.
// Raw s_barrier (not __syncthreads) so the compiler can't re-insert vmcnt(0);
// asm "memory" clobbers + sched_barrier(0) pin loads to their phase (rule 18).
//
// Grid is 1-D with a batch->XCD affinity swizzle (unchanged): all 64 tiles of
// batch b get linear ids == b (mod 8) so one batch's 3 MB bf16 slice lives in
// one XCD's L2 while its blocks run.
//
// LDS layout is XOR-swizzled (verified SQ_LDS_BANK_CONFLICT = 0) and
// compatible with global_load_lds's lane-ordered destination:
//   physical 16B block p of row r holds logical k-block l = p ^ ((r>>1)&3).
// ---------------------------------------------------------------------------
__global__ __launch_bounds__(256) void trilinear_gemm(
    const unsigned short* __restrict__ Qb, const unsigned short* __restrict__ Kb,
    const float* __restrict__ qlog, const float* __restrict__ klog,
    float* __restrict__ out)
{
    __shared__ __align__(16) unsigned short As[3][128 * 32];   // 3 x 8 KB
    __shared__ __align__(16) unsigned short Bs[3][128 * 32];   // 3 x 8 KB

    const int tid  = threadIdx.x;
    const int w    = tid >> 6, lane = tid & 63;
    const int wq   = w >> 1, wk = w & 1;

    // batch->XCD swizzle: id = g + 8*(t + 64*(b>>3)), g = b&7, t = qt*8+kt
    const int id = blockIdx.x;
    const int g  = id & 7;
    const int j  = id >> 3;            // 0..255
    const int b  = g + ((j >> 6) << 3);
    const int t0 = j & 63;
    const int qt = t0 >> 3, kt = t0 & 7;

    const unsigned short* Ag = Qb + ((size_t)b * LL + qt * 128) * DD;
    const unsigned short* Bg = Kb + ((size_t)b * LL + kt * 128) * DD;

    // staging addresses (swizzled column pick per lane)
    const int srow  = lane >> 2;                             // 0..15 per issue
    const int scol  = ((lane & 3) ^ ((lane >> 3) & 3)) * 8;  // swizzled k-chunk
    // fragment-read constants
    const int m    = lane & 15;
    const int l    = lane >> 4;                              // logical k-block
    const int p8   = (l ^ ((m >> 1) & 3)) * 8;               // physical k-chunk

    f32x4 acc[4][4] = {};

    // stage K-tile kt_ (4 x global_load_lds / thread) into ring slot s_
    #define STAGE(kt_, s_) do {                                                  \
        const int k0_ = (kt_) * 32;                                              \
        _Pragma("unroll")                                                        \
        for (int j2 = 0; j2 < 2; ++j2) {                                         \
            const int rb_ = w * 32 + j2 * 16;      /* wave-uniform row base */   \
            __builtin_amdgcn_global_load_lds(                                    \
                (const __attribute__((address_space(1))) void*)                  \
                    (Ag + (size_t)(rb_ + srow) * DD + k0_ + scol),               \
                (__attribute__((address_space(3))) void*)&As[s_][rb_ * 32],      \
                16, 0, 0);                                                       \
            __builtin_amdgcn_global_load_lds(                                    \
                (const __attribute__((address_space(1))) void*)                  \
                    (Bg + (size_t)(rb_ + srow) * DD + k0_ + scol),               \
                (__attribute__((address_space(3))) void*)&Bs[s_][rb_ * 32],      \
                16, 0, 0);                                                       \
        }                                                                        \
    } while (0)

    // ds_read fragments from slot s_, drain lgkm, then 16 MFMA.
    // lgkmcnt(0)+sched_barrier BEFORE the MFMAs: guarantees all ds_reads of
    // this tile completed before this iteration's closing barrier, so the
    // stage into this slot two tiles later can never race them (rule 18).
    #define COMPUTE(s_) do {                                                     \
        const unsigned short* A_ = As[s_];                                       \
        const unsigned short* B_ = Bs[s_];                                       \
        bf16x8 av[4], bv[4];                                                     \
        _Pragma("unroll")                                                        \
        for (int tt = 0; tt < 4; ++tt) {                                         \
            av[tt] = *(const bf16x8*)&A_[(wq * 64 + tt * 16 + m) * 32 + p8];     \
            bv[tt] = *(const bf16x8*)&B_[(wk * 64 + tt * 16 + m) * 32 + p8];     \
        }                                                                        \
        asm volatile("s_waitcnt lgkmcnt(0)" ::: "memory");                       \
        __builtin_amdgcn_sched_barrier(0);                                       \
        _Pragma("unroll")                                                        \
        for (int at = 0; at < 4; ++at)                                           \
            _Pragma("unroll")                                                    \
            for (int bt = 0; bt < 4; ++bt)                                       \
                acc[at][bt] = __builtin_amdgcn_mfma_f32_16x16x32_bf16(           \
                    av[at], bv[bt], acc[at][bt], 0, 0, 0);                       \
    } while (0)

    const int NT = DD / 32;   // 24 K-tiles

    // prologue: tiles 0 and 1 issued; wait only for tile 0 (tile 1 in flight)
    STAGE(0, 0);
    STAGE(1, 1);
    asm volatile("s_waitcnt vmcnt(4)" ::: "memory");
    __builtin_amdgcn_s_barrier();
    __builtin_amdgcn_sched_barrier(0);

    // steady state: issue t+2, compute t, wait for t+1 only (vmcnt(4))
    int bc = 0, bs = 2;
    for (int t = 0; t < NT - 2; ++t) {
        STAGE(t + 2, bs);
        COMPUTE(bc);
        asm volatile("s_waitcnt vmcnt(4)" ::: "memory");
        __builtin_amdgcn_s_barrier();
        __builtin_amdgcn_sched_barrier(0);
        bc = (bc == 2) ? 0 : bc + 1;
        bs = (bs == 2) ? 0 : bs + 1;
    }
    // epilogue of the pipeline: drain the last in-flight tile, compute both
    COMPUTE(bc);                                   // tile NT-2
    asm volatile("s_waitcnt vmcnt(0)" ::: "memory");
    __builtin_amdgcn_s_barrier();
    __builtin_amdgcn_sched_barrier(0);
    bc = (bc == 2) ? 0 : bc + 1;
    COMPUTE(bc);                                   // tile NT-1

    #undef STAGE
    #undef COMPUTE

    // epilogue: C/D layout col = lane&15, row = (lane>>4)*4 + reg  [m89/m91]
    const int qrow0 = qt * 128 + wq * 64;
    const int kcol0 = kt * 128 + wk * 64;
    const float* ql = qlog + b * LL + qrow0;
    const float* kl = klog + b * LL + kcol0;
    float* outp = out + ((size_t)b * LL + qrow0) * LL + kcol0;
    const int col = lane & 15, r4 = (lane >> 4) * 4;

    #pragma unroll
    for (int at = 0; at < 4; ++at) {
        #pragma unroll
        for (int bt = 0; bt < 4; ++bt) {
            const float klv = kl[bt * 16 + col];
            #pragma unroll
            for (int r = 0; r < 4; ++r) {
                const int row = at * 16 + r4 + r;
                outp[(size_t)row * LL + bt * 16 + col] = acc[at][bt][r] + ql[row] + klv;
            }
        }
    }
}

extern "C" void kernel_launch(void* const* d_in, const int* in_sizes, int n_in,
                              void* d_out, int out_size, void* d_ws, size_t ws_size,
                              hipStream_t stream) {
    const float* Q  = (const float*)d_in[0];
    const float* K  = (const float*)d_in[1];
    const float* w1 = (const float*)d_in[2];
    const float* w2 = (const float*)d_in[3];
    const float* w3 = (const float*)d_in[4];
    float* out = (float*)d_out;

    // workspace layout: Qb (bf16), Kb (bf16 of w3*K), qlog, klog
    unsigned short* Qb = (unsigned short*)d_ws;
    unsigned short* Kb = Qb + (size_t)BB * LL * DD;
    float* qlog = (float*)(Kb + (size_t)BB * LL * DD);
    float* klog = qlog + BB * LL;

    convert_kernel<<<BB * LL / 4, 256, 0, stream>>>(Q, K, w1, w2, w3, Qb, Kb, qlog, klog);
    trilinear_gemm<<<2048, 256, 0, stream>>>(Qb, Kb, qlog, klog, out);
}